// Round 1
// 81.002 us; speedup vs baseline: 1.0438x; 1.0438x over previous
//
#include <hip/hip_runtime.h>
#include <math.h>

#define N        512
#define DIM      256
#define NTHR     512            // 8 waves per block, one row per thread
#define APB      2              // anchors per block
#define NBLOCKS  (N / APB)      // 256
#define SCALING  10.0f
#define EPS      1e-12f

// Fused single-kernel design:
//   grid = 256 blocks x 512 threads (2x the wave count of the previous version).
//   Each block owns APB=2 anchors; thread t computes the distance of row t to both
//   anchors (one float4 stream per thread; anchor rows are block-uniform -> SMEM loads).
//   Ballot-compacted pos/neg lists (32 LDS atomics per block instead of 1024).
//   Pair loop uses pre-scaled distances: sigmoid = rcp(1 + exp(dn - dp)).
//   Finalize is fused via last-block-done: a 4-byte memset zeroes the arrival counter,
//   partials are published with agent-scope atomics, and the last-arriving block folds
//   all 256 partials with a fixed-order double-precision tree (deterministic result).
__global__ __launch_bounds__(NTHR) void triplet_kernel(
    const float* __restrict__ feat, const int* __restrict__ y,
    float* __restrict__ block_sum, float* __restrict__ block_cnt,
    unsigned int* __restrict__ done_ctr, float* __restrict__ out)
{
    __shared__ float  pos_d[APB][N];
    __shared__ float  neg_d[APB][N];
    __shared__ int    n_pos[APB], n_neg[APB];
    __shared__ float  red_s[NTHR / 64];
    __shared__ double fin_s[NBLOCKS];
    __shared__ double fin_c[NBLOCKS];
    __shared__ int    lastflag;

    const int tid  = threadIdx.x;
    const int bid  = blockIdx.x;
    const int a0   = bid * APB;
    const int lane = tid & 63;

    if (tid < APB) { n_pos[tid] = 0; n_neg[tid] = 0; }
    __syncthreads();

    // ---------- distance pass: thread tid owns row j = tid ----------
    const float4* f4   = reinterpret_cast<const float4*>(feat);
    const float4* rowj = f4 + tid * (DIM / 4);
    const float4* ra0  = f4 + a0 * (DIM / 4);   // block-uniform address -> s_load
    const float4* ra1  = ra0 + (DIM / 4);       // block-uniform address -> s_load
    float acc0 = 0.0f, acc1 = 0.0f;
    #pragma unroll 8
    for (int k = 0; k < DIM / 4; ++k) {
        const float4 v  = rowj[k];
        const float4 u0 = ra0[k];
        const float4 u1 = ra1[k];
        float e;
        e = v.x - u0.x; acc0 += e * e;
        e = v.y - u0.y; acc0 += e * e;
        e = v.z - u0.z; acc0 += e * e;
        e = v.w - u0.w; acc0 += e * e;
        e = v.x - u1.x; acc1 += e * e;
        e = v.y - u1.y; acc1 += e * e;
        e = v.z - u1.z; acc1 += e * e;
        e = v.w - u1.w; acc1 += e * e;
    }
    // pre-scale by SCALING so the pair loop is a single subtract
    const float d0 = SCALING * sqrtf(fmaxf(acc0, EPS));
    const float d1 = SCALING * sqrtf(fmaxf(acc1, EPS));

    const int yj  = y[tid];
    const int ya0 = y[a0];       // uniform -> s_load
    const int ya1 = y[a0 + 1];   // uniform -> s_load

    // ---------- ballot-compacted classification (32 LDS atomics / block) ----------
    const unsigned long long below = (1ull << lane) - 1ull;
    {
        const bool ip  = (yj == ya0) & (tid != a0);
        const bool ineg = (yj != ya0);
        const unsigned long long mp = __ballot(ip);
        const unsigned long long mn = __ballot(ineg);
        int bp = 0, bn = 0;
        if (lane == 0) {
            bp = atomicAdd(&n_pos[0], (int)__popcll(mp));
            bn = atomicAdd(&n_neg[0], (int)__popcll(mn));
        }
        bp = __shfl(bp, 0, 64);
        bn = __shfl(bn, 0, 64);
        if (ip)   pos_d[0][bp + (int)__popcll(mp & below)] = d0;
        if (ineg) neg_d[0][bn + (int)__popcll(mn & below)] = d0;
    }
    {
        const bool ip  = (yj == ya1) & (tid != a0 + 1);
        const bool ineg = (yj != ya1);
        const unsigned long long mp = __ballot(ip);
        const unsigned long long mn = __ballot(ineg);
        int bp = 0, bn = 0;
        if (lane == 0) {
            bp = atomicAdd(&n_pos[1], (int)__popcll(mp));
            bn = atomicAdd(&n_neg[1], (int)__popcll(mn));
        }
        bp = __shfl(bp, 0, 64);
        bn = __shfl(bn, 0, 64);
        if (ip)   pos_d[1][bp + (int)__popcll(mp & below)] = d1;
        if (ineg) neg_d[1][bn + (int)__popcll(mn & below)] = d1;
    }
    __syncthreads();

    // ---------- sigmoid over valid (p, n) pairs ----------
    float acc = 0.0f;
    int   cnt = 0;
    #pragma unroll
    for (int q = 0; q < APB; ++q) {
        const int np = n_pos[q];
        const int nn = n_neg[q];
        cnt += np * nn;
        for (int p = 0; p < np; ++p) {
            const float dp = pos_d[q][p];                    // broadcast LDS read
            for (int n = tid; n < nn; n += NTHR) {
                const float e = __expf(neg_d[q][n] - dp);    // exp(-x), x = s*(dp-dn)
                acc += __fdividef(1.0f, 1.0f + e);
            }
        }
    }

    // ---------- block reduce (wave shuffle, then cross-wave LDS) ----------
    #pragma unroll
    for (int s = 32; s > 0; s >>= 1)
        acc += __shfl_down(acc, s, 64);
    if (lane == 0) red_s[tid >> 6] = acc;
    __syncthreads();

    if (tid == 0) {
        float t = 0.0f;
        #pragma unroll
        for (int w = 0; w < NTHR / 64; ++w) t += red_s[w];
        __hip_atomic_store(&block_sum[bid], t, __ATOMIC_RELAXED, __HIP_MEMORY_SCOPE_AGENT);
        __hip_atomic_store(&block_cnt[bid], (float)cnt, __ATOMIC_RELAXED, __HIP_MEMORY_SCOPE_AGENT);
        const unsigned int prev =
            __hip_atomic_fetch_add(done_ctr, 1u, __ATOMIC_ACQ_REL, __HIP_MEMORY_SCOPE_AGENT);
        lastflag = (prev == NBLOCKS - 1) ? 1 : 0;
    }
    __syncthreads();

    // ---------- last-arriving block folds the 256 partials (fixed-order tree) ----------
    if (lastflag) {
        if (tid < NBLOCKS) {
            const float s = __hip_atomic_load(&block_sum[tid], __ATOMIC_RELAXED, __HIP_MEMORY_SCOPE_AGENT);
            const float c = __hip_atomic_load(&block_cnt[tid], __ATOMIC_RELAXED, __HIP_MEMORY_SCOPE_AGENT);
            fin_s[tid] = (double)s;
            fin_c[tid] = (double)c;
        }
        __syncthreads();
        for (int st = NBLOCKS / 2; st > 0; st >>= 1) {
            if (tid < st) { fin_s[tid] += fin_s[tid + st]; fin_c[tid] += fin_c[tid + st]; }
            __syncthreads();
        }
        if (tid == 0) out[0] = (float)(fin_s[0] / fin_c[0]);
    }
}

extern "C" void kernel_launch(void* const* d_in, const int* in_sizes, int n_in,
                              void* d_out, int out_size, void* d_ws, size_t ws_size,
                              hipStream_t stream) {
    const float* feat = (const float*)d_in[0];
    // d_in[1] = logits: unused by the loss
    const int* y = (const int*)d_in[2];

    float* block_sum = (float*)d_ws;                          // NBLOCKS floats
    float* block_cnt = block_sum + NBLOCKS;                   // NBLOCKS floats
    unsigned int* done_ctr = (unsigned int*)(block_cnt + NBLOCKS);

    hipMemsetAsync(done_ctr, 0, sizeof(unsigned int), stream);
    triplet_kernel<<<NBLOCKS, NTHR, 0, stream>>>(feat, y, block_sum, block_cnt,
                                                 done_ctr, (float*)d_out);
}

// Round 2
// 77.351 us; speedup vs baseline: 1.0930x; 1.0472x over previous
//
#include <hip/hip_runtime.h>
#include <math.h>

#define N        512
#define DIM      256
#define NTHR     512            // 8 waves per block
#define APB      2              // anchors per block
#define NBLOCKS  (N / APB)      // 256
#define SCALING  10.0f
#define EPS      1e-12f

// v3: coalesced distance pass.
//   Previous versions mapped lane i -> row i, so each wave load touched 64 distinct
//   cache lines (1 KB stride) -> L1 address-divergence bound (~30 us), insensitive
//   to occupancy. Now 16 lanes cooperate per row: lane reads float4 index
//   (lane&15) + 16c, so one instruction covers 4 rows x 256 B fully dense; a 4-step
//   shfl_xor reduce within 16-lane groups yields d^2. Distances go to LDS; the
//   ballot compaction + pair loop + last-block-done finalize are unchanged.
__global__ __launch_bounds__(NTHR) void triplet_kernel(
    const float* __restrict__ feat, const int* __restrict__ y,
    float* __restrict__ block_sum, float* __restrict__ block_cnt,
    unsigned int* __restrict__ done_ctr, float* __restrict__ out)
{
    __shared__ float  d_a[APB][N];       // scaled distances for all rows
    __shared__ float  pos_d[APB][N];
    __shared__ float  neg_d[APB][N];
    __shared__ int    n_pos[APB], n_neg[APB];
    __shared__ float  red_s[NTHR / 64];
    __shared__ double fin_s[NBLOCKS];
    __shared__ double fin_c[NBLOCKS];
    __shared__ int    lastflag;

    const int tid  = threadIdx.x;
    const int bid  = blockIdx.x;
    const int a0   = bid * APB;
    const int lane = tid & 63;
    const int wv   = tid >> 6;      // wave id 0..7
    const int seg  = lane & 15;     // 16-lane row group position
    const int sub  = lane >> 4;     // which of 4 rows this pass

    if (tid < APB) { n_pos[tid] = 0; n_neg[tid] = 0; }

    // ---- anchor fragments in registers: float4 index seg + 16c ----
    const float4* f4 = reinterpret_cast<const float4*>(feat);
    float4 u0[4], u1[4];
    #pragma unroll
    for (int c = 0; c < 4; ++c) {
        u0[c] = f4[(a0    ) * (DIM / 4) + seg + 16 * c];
        u1[c] = f4[(a0 + 1) * (DIM / 4) + seg + 16 * c];
    }

    // ---- coalesced distance pass: wave wv owns rows [wv*64, wv*64+64) ----
    #pragma unroll 4
    for (int t = 0; t < 16; ++t) {
        const int r = (wv << 6) + (t << 2) + sub;
        const float4* rp = f4 + r * (DIM / 4);
        float acc0 = 0.0f, acc1 = 0.0f;
        #pragma unroll
        for (int c = 0; c < 4; ++c) {
            const float4 v = rp[seg + 16 * c];   // lanes 0..15 cover 256 B dense
            float e;
            e = v.x - u0[c].x; acc0 += e * e;
            e = v.y - u0[c].y; acc0 += e * e;
            e = v.z - u0[c].z; acc0 += e * e;
            e = v.w - u0[c].w; acc0 += e * e;
            e = v.x - u1[c].x; acc1 += e * e;
            e = v.y - u1[c].y; acc1 += e * e;
            e = v.z - u1[c].z; acc1 += e * e;
            e = v.w - u1[c].w; acc1 += e * e;
        }
        #pragma unroll
        for (int s = 1; s < 16; s <<= 1) {
            acc0 += __shfl_xor(acc0, s, 16);
            acc1 += __shfl_xor(acc1, s, 16);
        }
        if (seg == 0) {     // lanes 0,16,32,48 write rows r..r+3 (adjacent banks)
            d_a[0][r] = SCALING * sqrtf(fmaxf(acc0, EPS));
            d_a[1][r] = SCALING * sqrtf(fmaxf(acc1, EPS));
        }
    }
    __syncthreads();

    // ---- ballot-compacted classification (thread tid <-> row tid) ----
    const float d0  = d_a[0][tid];
    const float d1  = d_a[1][tid];
    const int   yj  = y[tid];
    const int   ya0 = y[a0];
    const int   ya1 = y[a0 + 1];
    const unsigned long long below = (1ull << lane) - 1ull;
    {
        const bool ip   = (yj == ya0) & (tid != a0);
        const bool ineg = (yj != ya0);
        const unsigned long long mp = __ballot(ip);
        const unsigned long long mn = __ballot(ineg);
        int bp = 0, bn = 0;
        if (lane == 0) {
            bp = atomicAdd(&n_pos[0], (int)__popcll(mp));
            bn = atomicAdd(&n_neg[0], (int)__popcll(mn));
        }
        bp = __shfl(bp, 0, 64);
        bn = __shfl(bn, 0, 64);
        if (ip)   pos_d[0][bp + (int)__popcll(mp & below)] = d0;
        if (ineg) neg_d[0][bn + (int)__popcll(mn & below)] = d0;
    }
    {
        const bool ip   = (yj == ya1) & (tid != a0 + 1);
        const bool ineg = (yj != ya1);
        const unsigned long long mp = __ballot(ip);
        const unsigned long long mn = __ballot(ineg);
        int bp = 0, bn = 0;
        if (lane == 0) {
            bp = atomicAdd(&n_pos[1], (int)__popcll(mp));
            bn = atomicAdd(&n_neg[1], (int)__popcll(mn));
        }
        bp = __shfl(bp, 0, 64);
        bn = __shfl(bn, 0, 64);
        if (ip)   pos_d[1][bp + (int)__popcll(mp & below)] = d1;
        if (ineg) neg_d[1][bn + (int)__popcll(mn & below)] = d1;
    }
    __syncthreads();

    // ---- sigmoid over valid (p, n) pairs (distances pre-scaled by SCALING) ----
    float acc = 0.0f;
    int   cnt = 0;
    #pragma unroll
    for (int q = 0; q < APB; ++q) {
        const int np = n_pos[q];
        const int nn = n_neg[q];
        cnt += np * nn;
        for (int p = 0; p < np; ++p) {
            const float dp = pos_d[q][p];                    // broadcast LDS read
            for (int n = tid; n < nn; n += NTHR) {
                const float e = __expf(neg_d[q][n] - dp);    // exp(-x), x = dp - dn
                acc += __fdividef(1.0f, 1.0f + e);
            }
        }
    }

    // ---- block reduce ----
    #pragma unroll
    for (int s = 32; s > 0; s >>= 1)
        acc += __shfl_down(acc, s, 64);
    if (lane == 0) red_s[wv] = acc;
    __syncthreads();

    if (tid == 0) {
        float t = 0.0f;
        #pragma unroll
        for (int w = 0; w < NTHR / 64; ++w) t += red_s[w];
        __hip_atomic_store(&block_sum[bid], t, __ATOMIC_RELAXED, __HIP_MEMORY_SCOPE_AGENT);
        __hip_atomic_store(&block_cnt[bid], (float)cnt, __ATOMIC_RELAXED, __HIP_MEMORY_SCOPE_AGENT);
        const unsigned int prev =
            __hip_atomic_fetch_add(done_ctr, 1u, __ATOMIC_ACQ_REL, __HIP_MEMORY_SCOPE_AGENT);
        lastflag = (prev == NBLOCKS - 1) ? 1 : 0;
    }
    __syncthreads();

    // ---- last-arriving block folds the 256 partials (fixed-order tree) ----
    if (lastflag) {
        if (tid < NBLOCKS) {
            const float s = __hip_atomic_load(&block_sum[tid], __ATOMIC_RELAXED, __HIP_MEMORY_SCOPE_AGENT);
            const float c = __hip_atomic_load(&block_cnt[tid], __ATOMIC_RELAXED, __HIP_MEMORY_SCOPE_AGENT);
            fin_s[tid] = (double)s;
            fin_c[tid] = (double)c;
        }
        __syncthreads();
        for (int st = NBLOCKS / 2; st > 0; st >>= 1) {
            if (tid < st) { fin_s[tid] += fin_s[tid + st]; fin_c[tid] += fin_c[tid + st]; }
            __syncthreads();
        }
        if (tid == 0) out[0] = (float)(fin_s[0] / fin_c[0]);
    }
}

extern "C" void kernel_launch(void* const* d_in, const int* in_sizes, int n_in,
                              void* d_out, int out_size, void* d_ws, size_t ws_size,
                              hipStream_t stream) {
    const float* feat = (const float*)d_in[0];
    // d_in[1] = logits: unused by the loss
    const int* y = (const int*)d_in[2];

    float* block_sum = (float*)d_ws;                          // NBLOCKS floats
    float* block_cnt = block_sum + NBLOCKS;                   // NBLOCKS floats
    unsigned int* done_ctr = (unsigned int*)(block_cnt + NBLOCKS);

    hipMemsetAsync(done_ctr, 0, sizeof(unsigned int), stream);
    triplet_kernel<<<NBLOCKS, NTHR, 0, stream>>>(feat, y, block_sum, block_cnt,
                                                 done_ctr, (float*)d_out);
}

// Round 3
// 74.613 us; speedup vs baseline: 1.1331x; 1.0367x over previous
//
#include <hip/hip_runtime.h>
#include <math.h>

#define N        512
#define DIM      256
#define NTHR     512            // 8 waves per block
#define APB      2              // anchors per block
#define NBLOCKS  (N / APB)      // 256
#define SCALING  10.0f
#define EPS      1e-12f

// v4: single-dispatch iteration.
//   - done counter + per-block partials live in __device__ globals (NOT the
//     poisoned workspace), so the hipMemsetAsync node is gone: exactly one
//     dispatch per timed iteration. The last-arriving block resets the counter
//     for the next graph replay (stream order separates iterations).
//   - fold tail slimmed: shuffle-based double reduction (1 __syncthreads)
//     instead of an 8-round LDS tree.
//   - distance pass keeps the r2 coalesced 16-lane-per-row scheme; pair loop
//     holds each thread's negative in a register and loops over broadcast
//     positives.
__device__ float        g_block_sum[NBLOCKS];
__device__ float        g_block_cnt[NBLOCKS];
__device__ unsigned int g_done = 0;   // zero at module load; self-resetting

__global__ __launch_bounds__(NTHR) void triplet_kernel(
    const float* __restrict__ feat, const int* __restrict__ y,
    float* __restrict__ out)
{
    __shared__ float d_a[APB][N];        // scaled distances for all rows
    __shared__ float pos_d[APB][N];
    __shared__ float neg_d[APB][N];
    __shared__ int   n_pos[APB], n_neg[APB];
    __shared__ float red_s[NTHR / 64];
    __shared__ double fred_s[4];
    __shared__ double fred_c[4];
    __shared__ int   lastflag;

    const int tid  = threadIdx.x;
    const int bid  = blockIdx.x;
    const int a0   = bid * APB;
    const int lane = tid & 63;
    const int wv   = tid >> 6;      // wave id 0..7
    const int seg  = lane & 15;     // position within 16-lane row group
    const int sub  = lane >> 4;     // which of 4 rows per pass

    if (tid < APB) { n_pos[tid] = 0; n_neg[tid] = 0; }

    // ---- anchor fragments in registers: float4 index seg + 16c ----
    const float4* f4 = reinterpret_cast<const float4*>(feat);
    float4 u0[4], u1[4];
    #pragma unroll
    for (int c = 0; c < 4; ++c) {
        u0[c] = f4[(a0    ) * (DIM / 4) + seg + 16 * c];
        u1[c] = f4[(a0 + 1) * (DIM / 4) + seg + 16 * c];
    }

    // ---- coalesced distance pass: wave wv owns rows [wv*64, wv*64+64) ----
    #pragma unroll 4
    for (int t = 0; t < 16; ++t) {
        const int r = (wv << 6) + (t << 2) + sub;
        const float4* rp = f4 + r * (DIM / 4);
        float acc0 = 0.0f, acc1 = 0.0f;
        #pragma unroll
        for (int c = 0; c < 4; ++c) {
            const float4 v = rp[seg + 16 * c];   // lanes 0..15 cover 256 B dense
            float e;
            e = v.x - u0[c].x; acc0 += e * e;
            e = v.y - u0[c].y; acc0 += e * e;
            e = v.z - u0[c].z; acc0 += e * e;
            e = v.w - u0[c].w; acc0 += e * e;
            e = v.x - u1[c].x; acc1 += e * e;
            e = v.y - u1[c].y; acc1 += e * e;
            e = v.z - u1[c].z; acc1 += e * e;
            e = v.w - u1[c].w; acc1 += e * e;
        }
        #pragma unroll
        for (int s = 1; s < 16; s <<= 1) {
            acc0 += __shfl_xor(acc0, s, 16);
            acc1 += __shfl_xor(acc1, s, 16);
        }
        if (seg == 0) {
            d_a[0][r] = SCALING * sqrtf(fmaxf(acc0, EPS));
            d_a[1][r] = SCALING * sqrtf(fmaxf(acc1, EPS));
        }
    }
    __syncthreads();

    // ---- ballot-compacted classification (thread tid <-> row tid) ----
    const float d0  = d_a[0][tid];
    const float d1  = d_a[1][tid];
    const int   yj  = y[tid];
    const int   ya0 = y[a0];
    const int   ya1 = y[a0 + 1];
    const unsigned long long below = (1ull << lane) - 1ull;
    {
        const bool ip   = (yj == ya0) & (tid != a0);
        const bool ineg = (yj != ya0);
        const unsigned long long mp = __ballot(ip);
        const unsigned long long mn = __ballot(ineg);
        int bp = 0, bn = 0;
        if (lane == 0) {
            bp = atomicAdd(&n_pos[0], (int)__popcll(mp));
            bn = atomicAdd(&n_neg[0], (int)__popcll(mn));
        }
        bp = __shfl(bp, 0, 64);
        bn = __shfl(bn, 0, 64);
        if (ip)   pos_d[0][bp + (int)__popcll(mp & below)] = d0;
        if (ineg) neg_d[0][bn + (int)__popcll(mn & below)] = d0;
    }
    {
        const bool ip   = (yj == ya1) & (tid != a0 + 1);
        const bool ineg = (yj != ya1);
        const unsigned long long mp = __ballot(ip);
        const unsigned long long mn = __ballot(ineg);
        int bp = 0, bn = 0;
        if (lane == 0) {
            bp = atomicAdd(&n_pos[1], (int)__popcll(mp));
            bn = atomicAdd(&n_neg[1], (int)__popcll(mn));
        }
        bp = __shfl(bp, 0, 64);
        bn = __shfl(bn, 0, 64);
        if (ip)   pos_d[1][bp + (int)__popcll(mp & below)] = d1;
        if (ineg) neg_d[1][bn + (int)__popcll(mn & below)] = d1;
    }
    __syncthreads();

    // ---- sigmoid over valid (p, n) pairs: thread owns one negative ----
    float acc = 0.0f;
    int   cnt = 0;
    #pragma unroll
    for (int q = 0; q < APB; ++q) {
        const int np = n_pos[q];
        const int nn = n_neg[q];          // nn <= 511 < NTHR always
        cnt += np * nn;
        if (tid < nn) {
            const float dn = neg_d[q][tid];
            for (int p = 0; p < np; ++p) {
                const float e = __expf(dn - pos_d[q][p]);   // exp(-x), x = dp - dn
                acc += __fdividef(1.0f, 1.0f + e);
            }
        }
    }

    // ---- block reduce ----
    #pragma unroll
    for (int s = 32; s > 0; s >>= 1)
        acc += __shfl_down(acc, s, 64);
    if (lane == 0) red_s[wv] = acc;
    __syncthreads();

    if (tid == 0) {
        float t = 0.0f;
        #pragma unroll
        for (int w = 0; w < NTHR / 64; ++w) t += red_s[w];
        __hip_atomic_store(&g_block_sum[bid], t, __ATOMIC_RELAXED, __HIP_MEMORY_SCOPE_AGENT);
        __hip_atomic_store(&g_block_cnt[bid], (float)cnt, __ATOMIC_RELAXED, __HIP_MEMORY_SCOPE_AGENT);
        const unsigned int prev =
            __hip_atomic_fetch_add(&g_done, 1u, __ATOMIC_ACQ_REL, __HIP_MEMORY_SCOPE_AGENT);
        lastflag = (prev == NBLOCKS - 1) ? 1 : 0;
    }
    __syncthreads();

    // ---- last-arriving block: shuffle-fold the 256 partials ----
    if (lastflag) {
        double s = 0.0, c = 0.0;
        if (tid < NBLOCKS) {    // 4 waves participate
            s = (double)__hip_atomic_load(&g_block_sum[tid], __ATOMIC_RELAXED, __HIP_MEMORY_SCOPE_AGENT);
            c = (double)__hip_atomic_load(&g_block_cnt[tid], __ATOMIC_RELAXED, __HIP_MEMORY_SCOPE_AGENT);
        }
        if (tid < 256) {
            #pragma unroll
            for (int sh = 32; sh > 0; sh >>= 1) {
                s += __shfl_down(s, sh, 64);
                c += __shfl_down(c, sh, 64);
            }
            if (lane == 0) { fred_s[wv] = s; fred_c[wv] = c; }  // wv 0..3
        }
        __syncthreads();
        if (tid == 0) {
            const double ts = fred_s[0] + fred_s[1] + fred_s[2] + fred_s[3];
            const double tc = fred_c[0] + fred_c[1] + fred_c[2] + fred_c[3];
            out[0] = (float)(ts / tc);
            __hip_atomic_store(&g_done, 0u, __ATOMIC_RELAXED, __HIP_MEMORY_SCOPE_AGENT);
        }
    }
}

extern "C" void kernel_launch(void* const* d_in, const int* in_sizes, int n_in,
                              void* d_out, int out_size, void* d_ws, size_t ws_size,
                              hipStream_t stream) {
    const float* feat = (const float*)d_in[0];
    // d_in[1] = logits: unused by the loss
    const int* y = (const int*)d_in[2];
    triplet_kernel<<<NBLOCKS, NTHR, 0, stream>>>(feat, y, (float*)d_out);
}